// Round 6
// baseline (37.848 us; speedup 1.0000x reference)
//
#include <hip/hip_runtime.h>
#include <hip/hip_bf16.h>

// RotT: M = expm(-0.5i*angle*S), S = |0><1|+|1><0| on qudit 7 of 15 qutrits.
// y0[b] = c*x0[b] + s*(x1i[b], -x1r[b]); y1[b] = c*x1[b] + s*(x0i[b], -x0r[b]);
// y2 = x2. c=cos(angle/2), s=sin(angle/2). Partner of (a,j,b) is same b, other j.
//
// Output (verified round 4): 2*D bf16, interleaved IMAG-FIRST:
//   u32 per amplitude = (bf16(re)<<16) | bf16(im).
//
// Round 5 post-mortem: LDS staging + float4 loads worked (FETCH 63->56 MB) but
// 256-thr blocks x 35KB LDS capped occupancy at 33% -> latency-bound, 35.5us.
// This round: 512-thr blocks (4/CU = 100% occupancy cap), per-plane b-indexed
// LDS arrays so self-reads are aligned ds_read_b128 and ALL output stores are
// aligned uint4 (16B). Partner reads misaligned b32 (8-way conflict, cheap).

constexpr int PLANE  = 2187;   // 3^7
constexpr int ROWLEN = 6561;   // 3^8
constexpr int NROWS  = 2187;   // d_left
constexpr int LDSN   = 2192;   // PLANE + max shift 3 + pad

__device__ __forceinline__ uint32_t pack_bf2(float re, float im) {
    __hip_bfloat162 h;
    h.x = __float2bfloat16(im);      // low half  = imag (verified layout)
    h.y = __float2bfloat16(re);      // high half = real
    return *reinterpret_cast<uint32_t*>(&h);
}

__global__ __launch_bounds__(512, 8) void rot_kernel(
    const float* __restrict__ xr,
    const float* __restrict__ xi,
    const float* __restrict__ angle,
    uint32_t* __restrict__ out)
{
    __shared__ __align__(16) float s0r[LDSN], s0i[LDSN], s1r[LDSN], s1i[LDSN];

    const int tid = threadIdx.x;
    const int a   = blockIdx.x;

    const float half = 0.5f * angle[0];
    const float s = sinf(half);
    const float c = cosf(half);

    const int g0 = a * ROWLEN;           // plane-0 start
    const int g1 = g0 + PLANE;           // plane-1 start
    const int g2 = g1 + PLANE;           // plane-2 start

    const int sh0 = g0 & 3, pre0 = (4 - sh0) & 3, nq0 = (PLANE - pre0) >> 2;
    const int sh1 = g1 & 3, pre1 = (4 - sh1) & 3, nq1 = (PLANE - pre1) >> 2;
    const int sh2 = g2 & 3, pre2 = (4 - sh2) & 3, nq2 = (PLANE - pre2) >> 2;

    // ---- stage planes 0,1 into per-plane b-indexed LDS (aligned both sides) ----
    if (tid < pre0) { s0r[tid + sh0] = xr[g0 + tid]; s0i[tid + sh0] = xi[g0 + tid]; }
    if (tid < pre1) { s1r[tid + sh1] = xr[g1 + tid]; s1i[tid + sh1] = xi[g1 + tid]; }
    { int b = pre0 + 4 * nq0 + tid; if (b < PLANE) { s0r[b + sh0] = xr[g0 + b]; s0i[b + sh0] = xi[g0 + b]; } }
    { int b = pre1 + 4 * nq1 + tid; if (b < PLANE) { s1r[b + sh1] = xr[g1 + b]; s1i[b + sh1] = xi[g1 + b]; } }

    {
        const float4* gr = reinterpret_cast<const float4*>(xr + g0 + pre0);
        const float4* gi = reinterpret_cast<const float4*>(xi + g0 + pre0);
        float4* lr = reinterpret_cast<float4*>(&s0r[pre0 + sh0]);   // 0 or 4 -> aligned
        float4* li = reinterpret_cast<float4*>(&s0i[pre0 + sh0]);
        for (int q = tid; q < nq0; q += 512) { lr[q] = gr[q]; li[q] = gi[q]; }
    }
    {
        const float4* gr = reinterpret_cast<const float4*>(xr + g1 + pre1);
        const float4* gi = reinterpret_cast<const float4*>(xi + g1 + pre1);
        float4* lr = reinterpret_cast<float4*>(&s1r[pre1 + sh1]);
        float4* li = reinterpret_cast<float4*>(&s1i[pre1 + sh1]);
        for (int q = tid; q < nq1; q += 512) { lr[q] = gr[q]; li[q] = gi[q]; }
    }

    // ---- plane 2 passthrough (no LDS), overlaps staging drain ----
    {
        if (tid < pre2) { int idx = g2 + tid; out[idx] = pack_bf2(xr[idx], xi[idx]); }
        const float4* gr = reinterpret_cast<const float4*>(xr + g2 + pre2);
        const float4* gi = reinterpret_cast<const float4*>(xi + g2 + pre2);
        uint4* o4 = reinterpret_cast<uint4*>(out + g2 + pre2);
        for (int q = tid; q < nq2; q += 512) {
            float4 r = gr[q], i = gi[q];
            uint4 o;
            o.x = pack_bf2(r.x, i.x); o.y = pack_bf2(r.y, i.y);
            o.z = pack_bf2(r.z, i.z); o.w = pack_bf2(r.w, i.w);
            o4[q] = o;
        }
        int b = pre2 + 4 * nq2 + tid;
        if (b < PLANE) { int idx = g2 + b; out[idx] = pack_bf2(xr[idx], xi[idx]); }
    }

    __syncthreads();

    // ---- plane-0 outputs: aligned b128 self-reads, aligned uint4 stores ----
    if (tid < pre0) {
        int b = tid;
        out[g0 + b] = pack_bf2(c * s0r[b + sh0] + s * s1i[b + sh1],
                               c * s0i[b + sh0] - s * s1r[b + sh1]);
    }
    { int b = pre0 + 4 * nq0 + tid;
      if (b < PLANE)
        out[g0 + b] = pack_bf2(c * s0r[b + sh0] + s * s1i[b + sh1],
                               c * s0i[b + sh0] - s * s1r[b + sh1]); }
    for (int q = tid; q < nq0; q += 512) {
        int b = pre0 + 4 * q;
        float4 vr = *reinterpret_cast<const float4*>(&s0r[b + sh0]);
        float4 vi = *reinterpret_cast<const float4*>(&s0i[b + sh0]);
        int p = b + sh1;                 // partner (misaligned by +-1)
        uint4 o;
        o.x = pack_bf2(c * vr.x + s * s1i[p + 0], c * vi.x - s * s1r[p + 0]);
        o.y = pack_bf2(c * vr.y + s * s1i[p + 1], c * vi.y - s * s1r[p + 1]);
        o.z = pack_bf2(c * vr.z + s * s1i[p + 2], c * vi.z - s * s1r[p + 2]);
        o.w = pack_bf2(c * vr.w + s * s1i[p + 3], c * vi.w - s * s1r[p + 3]);
        *reinterpret_cast<uint4*>(out + g0 + b) = o;
    }

    // ---- plane-1 outputs: symmetric ----
    if (tid < pre1) {
        int b = tid;
        out[g1 + b] = pack_bf2(c * s1r[b + sh1] + s * s0i[b + sh0],
                               c * s1i[b + sh1] - s * s0r[b + sh0]);
    }
    { int b = pre1 + 4 * nq1 + tid;
      if (b < PLANE)
        out[g1 + b] = pack_bf2(c * s1r[b + sh1] + s * s0i[b + sh0],
                               c * s1i[b + sh1] - s * s0r[b + sh0]); }
    for (int q = tid; q < nq1; q += 512) {
        int b = pre1 + 4 * q;
        float4 vr = *reinterpret_cast<const float4*>(&s1r[b + sh1]);
        float4 vi = *reinterpret_cast<const float4*>(&s1i[b + sh1]);
        int p = b + sh0;
        uint4 o;
        o.x = pack_bf2(c * vr.x + s * s0i[p + 0], c * vi.x - s * s0r[p + 0]);
        o.y = pack_bf2(c * vr.y + s * s0i[p + 1], c * vi.y - s * s0r[p + 1]);
        o.z = pack_bf2(c * vr.z + s * s0i[p + 2], c * vi.z - s * s0r[p + 2]);
        o.w = pack_bf2(c * vr.w + s * s0i[p + 3], c * vi.w - s * s0r[p + 3]);
        *reinterpret_cast<uint4*>(out + g1 + b) = o;
    }
}

extern "C" void kernel_launch(void* const* d_in, const int* in_sizes, int n_in,
                              void* d_out, int out_size, void* d_ws, size_t ws_size,
                              hipStream_t stream) {
    // Inputs in setup_inputs() dict order: x_real (D), x_imag (D), angle (1).
    const float* big[2] = {nullptr, nullptr};
    const float* angle = nullptr;
    int nbig = 0;
    for (int i = 0; i < n_in; ++i) {
        if (in_sizes[i] == 1) angle = (const float*)d_in[i];
        else if (nbig < 2)    big[nbig++] = (const float*)d_in[i];
    }
    const float* xr = big[0];
    const float* xi = big[1];
    uint32_t* out = (uint32_t*)d_out;

    rot_kernel<<<NROWS, 512, 0, stream>>>(xr, xi, angle, out);
}